// Round 1
// baseline (648.374 us; speedup 1.0000x reference)
//
#include <hip/hip_runtime.h>

#define BB 16
#define CC 64
#define HH 256
#define WW 256
#define NM 512   // 32 ky-modes * 16 kx-modes

// ws layout: X[b][i][mode]{re,im}  (4 MB)  then  OUT[b][o][mode]{re,im} (4 MB)
// mode = ky_idx*16 + kx ; ky_idx 0..15 -> ky=ky_idx ; ky_idx 16..31 -> ky=224+ky_idx (240..255)

// ---------------- K1: forward partial DFT per (b,i) image ----------------
__global__ __launch_bounds__(256) void k_fwd(const float* __restrict__ x,
                                             float2* __restrict__ Xws) {
  const int blk = blockIdx.x;          // b*CC + i
  const int t   = threadIdx.x;

  __shared__ float  xs[32][WW + 1];    // 32 image rows, padded (bank-conflict-free)
  __shared__ float2 cis[256];          // (cos, sin)(2pi m/256)
  __shared__ float2 Tsh[32][16];       // row-DFT results for current chunk

  {
    float s, c;
    sincosf((float)t * 0.024543692606170259681f /*2pi/256*/, &s, &c);
    cis[t] = make_float2(c, s);
  }

  const int kx  = t & 15;              // this thread's kx mode
  const int ky0 = t >> 4;              // 0..15 ; second ky handled = 240+ky0
  float a0r = 0.f, a0i = 0.f, a1r = 0.f, a1i = 0.f;

  const float* img = x + (size_t)blk * (HH * WW);

  for (int chunk = 0; chunk < 8; ++chunk) {
    const int hbase = chunk * 32;
    __syncthreads();                   // guards xs/Tsh reuse across chunks (and cis on chunk 0)
    // coalesced float4 load of 32 rows into LDS
    const float4* src = (const float4*)(img + hbase * WW);
    #pragma unroll
    for (int i = 0; i < 8; ++i) {
      int idx = i * 256 + t;
      float4 v = src[idx];
      int r = idx >> 6;
      int c = (idx & 63) << 2;
      xs[r][c + 0] = v.x; xs[r][c + 1] = v.y; xs[r][c + 2] = v.z; xs[r][c + 3] = v.w;
    }
    __syncthreads();
    // phase 1: row DFT  T[h][k] = sum_w xs[h][w] * e^{-i 2pi k w/256}
    {
      const int h  = t & 31;
      const int k1 = t >> 5;           // 0..7, also handles k1+8
      const int k2 = k1 + 8;
      float t1r = 0.f, t1i = 0.f, t2r = 0.f, t2i = 0.f;
      int m1 = 0, m2 = 0;
      #pragma unroll 4
      for (int w = 0; w < WW; ++w) {
        float xv = xs[h][w];
        float2 c1 = cis[m1];
        float2 c2 = cis[m2];
        t1r = fmaf(xv, c1.x, t1r); t1i = fmaf(-xv, c1.y, t1i);
        t2r = fmaf(xv, c2.x, t2r); t2i = fmaf(-xv, c2.y, t2i);
        m1 = (m1 + k1) & 255;
        m2 = (m2 + k2) & 255;
      }
      Tsh[h][k1] = make_float2(t1r, t1i);
      Tsh[h][k2] = make_float2(t2r, t2i);
    }
    __syncthreads();
    // phase 2: accumulate ky-DFT   X += T[h] * e^{-i 2pi ky h/256}
    {
      int ma = (ky0 * hbase) & 255;
      int mb = ((240 + ky0) * hbase) & 255;
      const int da = ky0;
      const int db = 240 + ky0;        // step mod 256 applied below
      #pragma unroll 4
      for (int hl = 0; hl < 32; ++hl) {
        float2 tv = Tsh[hl][kx];
        float2 ea = cis[ma];
        float2 eb = cis[mb];
        // (tr + i ti) * (c - i s) = (tr c + ti s) + i(ti c - tr s)
        a0r = fmaf(tv.x, ea.x, fmaf(tv.y, ea.y, a0r));
        a0i = fmaf(tv.y, ea.x, fmaf(-tv.x, ea.y, a0i));
        a1r = fmaf(tv.x, eb.x, fmaf(tv.y, eb.y, a1r));
        a1i = fmaf(tv.y, eb.x, fmaf(-tv.x, eb.y, a1i));
        ma = (ma + da) & 255;
        mb = (mb + db) & 255;
      }
    }
  }
  // thread t owns mode t (ky=ky0) and mode t+256 (ky=240+ky0)
  Xws[(size_t)blk * NM + t]       = make_float2(a0r, a0i);
  Xws[(size_t)blk * NM + t + 256] = make_float2(a1r, a1i);
}

// ---------------- K2: per-mode complex channel mixing ----------------
__global__ __launch_bounds__(256) void k_mix(const float2* __restrict__ Xws,
                                             const float* __restrict__ w1r,
                                             const float* __restrict__ w1i,
                                             const float* __restrict__ w2r,
                                             const float* __restrict__ w2i,
                                             float2* __restrict__ OUTws) {
  const int mode   = blockIdx.x;       // ky_idx*16 + kx
  const int ky_idx = mode >> 4;
  const int kx     = mode & 15;
  const int m1     = ky_idx & 15;
  const bool top   = (ky_idx < 16);
  const float* wr  = top ? w1r : w2r;
  const float* wi  = top ? w1i : w2i;
  const int t = threadIdx.x;

  __shared__ float2 Xs[BB * CC];       // [b][i]  8 KB
  __shared__ float2 Ws[CC * CC];       // [i][o] 32 KB

  for (int j = t; j < BB * CC; j += 256)
    Xs[j] = Xws[(size_t)j * NM + mode];
  const int wbase = m1 * 16 + kx;      // w[i][o][m1][m2] strides: i:16384, o:256, m1:16, m2:1
  for (int e = t; e < CC * CC; e += 256) {
    size_t off = (size_t)e * 256 + wbase;
    Ws[e] = make_float2(wr[off], wi[off]);
  }
  __syncthreads();

  const int o = t & 63, bq = t >> 6;   // each thread: 4 batches x 1 out-channel
  float accr[4] = {0.f, 0.f, 0.f, 0.f};
  float acci[4] = {0.f, 0.f, 0.f, 0.f};
  for (int i = 0; i < CC; ++i) {
    float2 wv = Ws[i * CC + o];
    #pragma unroll
    for (int bb = 0; bb < 4; ++bb) {
      float2 xv = Xs[(bq * 4 + bb) * CC + i];   // wave-uniform -> LDS broadcast
      accr[bb] = fmaf(xv.x, wv.x, fmaf(-xv.y, wv.y, accr[bb]));
      acci[bb] = fmaf(xv.x, wv.y, fmaf( xv.y, wv.x, acci[bb]));
    }
  }
  #pragma unroll
  for (int bb = 0; bb < 4; ++bb) {
    int b = bq * 4 + bb;
    OUTws[(size_t)(b * CC + o) * NM + mode] = make_float2(accr[bb], acci[bb]);
  }
}

// ---------------- K3: inverse partial DFT per (b,o) image ----------------
__global__ __launch_bounds__(256) void k_inv(const float2* __restrict__ OUTws,
                                             float* __restrict__ out) {
  const int blk = blockIdx.x;          // b*CC + o
  const int t   = threadIdx.x;

  __shared__ float2 cis[256];          // 2 KB
  __shared__ float2 Fm[NM];            // 4 KB: modes [ky_idx][kx]
  __shared__ float2 Zs[64][16];        // 8 KB: Z for 64-row chunk

  {
    float s, c;
    sincosf((float)t * 0.024543692606170259681f, &s, &c);
    cis[t] = make_float2(c, s);
  }
  Fm[t]       = OUTws[(size_t)blk * NM + t];
  Fm[t + 256] = OUTws[(size_t)blk * NM + t + 256];
  __syncthreads();                     // cis/Fm visible to all

  // per-thread column twiddles (this thread owns output column w = t):
  // out[h][w] = sum_kx c_kx * (Zr*cos - Zi*sin)(2pi kx w/256) / 65536,  c_0=1, c_k=2
  float twr[16], twi[16];
  #pragma unroll
  for (int k = 0; k < 16; ++k) {
    float2 e = cis[(k * t) & 255];
    float sc = (k == 0 ? 1.f : 2.f) * (1.f / 65536.f);
    twr[k] = e.x * sc;
    twi[k] = e.y * sc;
  }

  float* oimg = out + (size_t)blk * (HH * WW);

  for (int chunk = 0; chunk < 4; ++chunk) {
    const int hbase = chunk * 64;
    __syncthreads();                   // Zs reuse guard
    // phase 1: Z[h][kx] = sum_{ky in K} F[ky][kx] * e^{+i 2pi ky h/256}
    {
      const int kxz = t & 15;
      const int hl0 = (t >> 4) * 4;    // 4 rows per thread
      #pragma unroll
      for (int j = 0; j < 4; ++j) {
        const int h = hbase + hl0 + j;
        float zr = 0.f, zi = 0.f;
        int mt = 0;                    // (ky*h)&255 for top, step h
        int mb = (240 * h) & 255;      // for bottom (ky=240..255), step h
        #pragma unroll 4
        for (int ki = 0; ki < 16; ++ki) {
          float2 ft = Fm[ki * 16 + kxz];
          float2 et = cis[mt];
          zr = fmaf(ft.x, et.x, fmaf(-ft.y, et.y, zr));
          zi = fmaf(ft.x, et.y, fmaf( ft.y, et.x, zi));
          float2 fb = Fm[(ki + 16) * 16 + kxz];
          float2 eb = cis[mb];
          zr = fmaf(fb.x, eb.x, fmaf(-fb.y, eb.y, zr));
          zi = fmaf(fb.x, eb.y, fmaf( fb.y, eb.x, zi));
          mt = (mt + h) & 255;
          mb = (mb + h) & 255;
        }
        Zs[hl0 + j][kxz] = make_float2(zr, zi);
      }
    }
    __syncthreads();
    // phase 2: 64 output rows; thread t owns column w=t; Zs reads are wave-uniform broadcasts
    #pragma unroll 2
    for (int hl = 0; hl < 64; ++hl) {
      float acc = 0.f;
      #pragma unroll
      for (int k = 0; k < 16; ++k) {
        float2 z = Zs[hl][k];
        acc = fmaf(z.x, twr[k], fmaf(-z.y, twi[k], acc));
      }
      oimg[(size_t)(hbase + hl) * WW + t] = acc;
    }
  }
}

extern "C" void kernel_launch(void* const* d_in, const int* in_sizes, int n_in,
                              void* d_out, int out_size, void* d_ws, size_t ws_size,
                              hipStream_t stream) {
  const float* x   = (const float*)d_in[0];
  const float* w1r = (const float*)d_in[1];
  const float* w1i = (const float*)d_in[2];
  const float* w2r = (const float*)d_in[3];
  const float* w2i = (const float*)d_in[4];
  float* out = (float*)d_out;

  float2* Xws   = (float2*)d_ws;                     // 524288 float2 = 4 MB
  float2* OUTws = Xws + (size_t)BB * CC * NM;        // 524288 float2 = 4 MB

  k_fwd<<<BB * CC, 256, 0, stream>>>(x, Xws);
  k_mix<<<NM, 256, 0, stream>>>(Xws, w1r, w1i, w2r, w2i, OUTws);
  k_inv<<<BB * CC, 256, 0, stream>>>(OUTws, out);
}